// Round 17
// baseline (339.461 us; speedup 1.0000x reference)
//
#include <hip/hip_runtime.h>
#include <hip/hip_bf16.h>

#define T_SEQ 2048
#define DIMD  1024
#define INNER 2048
#define STATE 64
#define BATCH 4
#define NCHUNK 64
#define CHUNK_L (T_SEQ / NCHUNK)   // 32
#define MROWS (BATCH * T_SEQ)      // 8192
#define PSTRIDE ((long)MROWS * STATE)

typedef __hip_bfloat16 bf16;
typedef __attribute__((ext_vector_type(8))) short bf16x8v;
typedef __attribute__((ext_vector_type(4))) float f32x4v;
typedef __attribute__((ext_vector_type(4))) short short4v;

__device__ __forceinline__ float b2f(short s) {
    unsigned u = ((unsigned)(unsigned short)s) << 16;
    float f;
    __builtin_memcpy(&f, &u, 4);
    return f;
}
__device__ __forceinline__ short f2b(float f) {
    bf16 h = __float2bfloat16(f);  // RNE
    short s;
    __builtin_memcpy(&s, &h, 2);
    return s;
}

// async global->LDS, 16B per lane. LDS dest must be lane-linear.
__device__ __forceinline__ void gld_lds16(void* lds, const void* gsrc) {
    __builtin_amdgcn_global_load_lds(
        (const __attribute__((address_space(1))) unsigned*)gsrc,
        (__attribute__((address_space(3))) unsigned*)lds, 16, 0, 0);
}

template<int N> __device__ __forceinline__ void waitcnt_vm() {
    if constexpr (N == 8)       asm volatile("s_waitcnt vmcnt(8)" ::: "memory");
    else if constexpr (N == 4)  asm volatile("s_waitcnt vmcnt(4)" ::: "memory");
    else if constexpr (N == 2)  asm volatile("s_waitcnt vmcnt(2)" ::: "memory");
    else                        asm volatile("s_waitcnt vmcnt(0)" ::: "memory");
}
template<int N> __device__ __forceinline__ void waitcnt_lgkm() {
    if constexpr (N == 12)      asm volatile("s_waitcnt lgkmcnt(12)" ::: "memory");
    else                        asm volatile("s_waitcnt lgkmcnt(0)" ::: "memory");
}
__device__ __forceinline__ void block_barrier() {
    asm volatile("" ::: "memory");
    __builtin_amdgcn_s_barrier();
    asm volatile("" ::: "memory");
}

// Block swizzle. Mode 1: XCD contiguous-chunk (nwg%8==0). Mode 2: region
// (4x4 blocks per region within an XCD strip; L2-resident panel sharing).
template<int XSWZ>
__device__ __forceinline__ void swz_block(int& bx, int& by) {
    if constexpr (XSWZ == 1) {
        const int gx = gridDim.x;
        const int nwg = gx * gridDim.y;
        int id = by * gx + bx;
        const int cpx = nwg >> 3;
        id = (id & 7) * cpx + (id >> 3);
        bx = id % gx; by = id / gx;
    } else if constexpr (XSWZ == 2) {
        const int gx = gridDim.x;
        const int gy = gridDim.y;
        const int id = by * gx + bx;
        const int xcd = id & 7;
        const int c   = id >> 3;
        const int rowsX = gy >> 3;
        const int rw  = gx >> 2;
        const int r   = c >> 4;
        const int pos = c & 15;
        const int rbx = (r % rw) << 2;
        const int rby = (r / rw) << 2;
        bx = rbx + (pos & 3);
        by = xcd * rowsX + rby + (pos >> 2);
    }
}

// ---------------------------------------------------------------------------
// 8-phase 256^2 GEMM — round 17: REG-LEVEL FRAGMENT DOUBLE-BUFFER with
// counted lgkmcnt. Phase h issues quadrant h+1's 12 ds_reads, then waits
// lgkmcnt(12) — retiring exactly phase h's reads (issued last phase) while
// h+1's stream through the LDS port UNDER the MFMA cluster. Breaks the
// ds_read->lgkm(0)->MFMA serialization that pinned all prior variants at
// ~36% MfmaUtil (cycle model: 3072 LDS + 2484 MFMA + 500 wr ~= 5895 meas).
// Fragment sets E/O alternate by phase parity (all indexing constant after
// unroll — rule 20). Quadrants Q = {(0,0),(1,0),(1,1),(0,1)} in (Ahalf,Bhalf).
// FIFO ledger (2 gloads/half, stage at phase h = half h of t+1):
//  (t,0): vmcnt(2) retires A1(t)  [needed by Q1 reads here]; barrier;
//         rd Q1->O; stage A0'; lgkm(12); MFMA Q0 (E).
//  (t,1): vmcnt(2) retires B1(t) [Q2 needs it]; barrier; rd Q2->E;
//         stage B0'; lgkm(12); MFMA Q1 (O).     [last tile: vmcnt(0)]
//  (t,2): no wait (Q3 = A0,B1 long published); rd Q3->O; stage A1';
//         lgkm(12); MFMA Q2 (E).
//  (t,3): vmcnt(2) retires A0',B0'; barrier; rd Q0'(buf^1)->E; stage B1';
//         lgkm(12); MFMA Q3 (O).                [last tile: lgkm(0), no rd]
//  Outstanding-gload trace: (t,0)top [A1,B1]=4 -> 2; (t,1)top [B1,A0']=4 -> 2;
//  (t,2)top [A0',B0']=4; (t,3)top [A0',B0',A1']=6 -> 2; (t+1,0)top [A1',B1']=4.
//  Closes inductively. Overwrite hazard: stage(t,h) writes buf[(t+1)&1] whose
//  prior readers (tile t-1) all completed before the (t,0) barrier.
//  Prologue: stage 4 halves t0; vmcnt(4); barrier; rd Q0->E.
// XOR swizzle: zero bank conflicts (round 6). Region XCD swizzle (round 12).
// ---------------------------------------------------------------------------
template<int EPI, int XSWZ>
__global__ __launch_bounds__(512, 2)
void gemm_8ph(const short* __restrict__ A, const short* __restrict__ B,
              void* __restrict__ Cout, int M, int N, int K)
{
    __shared__ __align__(16) short As[2][2][128 * 64];
    __shared__ __align__(16) short Bs[2][2][128 * 64];

    int bx = blockIdx.x, by = blockIdx.y;
    swz_block<XSWZ>(bx, by);

    const int tid  = threadIdx.x;
    const int lane = tid & 63;
    const int wave = tid >> 6;
    const int wm2 = (wave >> 2) & 1;
    const int wn2 = wave & 3;
    const long bm = (long)by * 256;
    const long bn = (long)bx * 256;

    const int rsel = lane & 15;
    const int ssrc = (((tid & 7) ^ ((tid >> 3) & 7)) * 8);
    const int swz  = lane & 7;

    const int QM4[4] = {0, 1, 1, 0};
    const int QN4[4] = {0, 0, 1, 1};

    f32x4v acc[4][4][2];
#pragma unroll
    for (int q = 0; q < 4; q++)
#pragma unroll
        for (int m = 0; m < 4; m++)
#pragma unroll
            for (int n = 0; n < 2; n++)
                acc[q][m][n] = (f32x4v){0.f, 0.f, 0.f, 0.f};

    const int nt = K / 64;

    auto stage_half = [&](int tt, int h) {
        const int buf = tt & 1;
        const int half = h >> 1;
        const int k0 = tt * 64;
#pragma unroll
        for (int i = 0; i < 2; i++) {
            const int j = i * 512 + tid;
            if (h & 1)
                gld_lds16(&Bs[buf][half][j * 8],
                          &B[(bn + half * 128 + (j >> 3)) * (long)K + k0 + ssrc]);
            else
                gld_lds16(&As[buf][half][j * 8],
                          &A[(bm + half * 128 + (j >> 3)) * (long)K + k0 + ssrc]);
        }
    };

    bf16x8v afE[4][2], bfE[2][2], afO[4][2], bfO[2][2];

    auto rd = [&](int rbuf, int q, bf16x8v (&Af)[4][2], bf16x8v (&Bf)[2][2]) {
        const int qm = QM4[q], qn = QN4[q];
#pragma unroll
        for (int kkh = 0; kkh < 2; kkh++) {
            const int slog = kkh * 4 + (lane >> 4);
            const int soff = ((slog ^ swz) * 8);
#pragma unroll
            for (int m = 0; m < 4; m++) {
                const int ar = wm2 * 64 + m * 16 + rsel;
                Af[m][kkh] = *(const bf16x8v*)&As[rbuf][qm][ar * 64 + soff];
            }
#pragma unroll
            for (int n = 0; n < 2; n++) {
                const int br = wn2 * 32 + n * 16 + rsel;
                Bf[n][kkh] = *(const bf16x8v*)&Bs[rbuf][qn][br * 64 + soff];
            }
        }
    };
    auto mm = [&](int q, bf16x8v (&Af)[4][2], bf16x8v (&Bf)[2][2]) {
        __builtin_amdgcn_s_setprio(1);
#pragma unroll
        for (int kkh = 0; kkh < 2; kkh++)
#pragma unroll
            for (int m = 0; m < 4; m++)
#pragma unroll
                for (int n = 0; n < 2; n++)
                    acc[q][m][n] = __builtin_amdgcn_mfma_f32_16x16x32_bf16(
                        Af[m][kkh], Bf[n][kkh], acc[q][m][n], 0, 0, 0);
        __builtin_amdgcn_s_setprio(0);
    };

    // prologue
    stage_half(0, 0); stage_half(0, 1); stage_half(0, 2); stage_half(0, 3);
    waitcnt_vm<4>();
    block_barrier();
    rd(0, 0, afE, bfE);

    for (int t = 0; t < nt; ++t) {
        const int buf = t & 1;
        const bool pf = (t + 1 < nt);
        // ---- phase 0: MFMA Q0(E), read Q1->O
        waitcnt_vm<2>();
        block_barrier();
        rd(buf, 1, afO, bfO);
        if (pf) stage_half(t + 1, 0);
        waitcnt_lgkm<12>();
        __builtin_amdgcn_sched_barrier(0);
        mm(0, afE, bfE);
        // ---- phase 1: MFMA Q1(O), read Q2->E
        if (pf) waitcnt_vm<2>();
        else    waitcnt_vm<0>();
        block_barrier();
        rd(buf, 2, afE, bfE);
        if (pf) stage_half(t + 1, 1);
        waitcnt_lgkm<12>();
        __builtin_amdgcn_sched_barrier(0);
        mm(1, afO, bfO);
        // ---- phase 2: MFMA Q2(E), read Q3->O (no wait: operands published)
        rd(buf, 3, afO, bfO);
        if (pf) stage_half(t + 1, 2);
        waitcnt_lgkm<12>();
        __builtin_amdgcn_sched_barrier(0);
        mm(2, afE, bfE);
        // ---- phase 3: MFMA Q3(O), read Q0'(buf^1)->E
        if (pf) {
            waitcnt_vm<2>();
            block_barrier();
            rd(buf ^ 1, 0, afE, bfE);
            stage_half(t + 1, 3);
            waitcnt_lgkm<12>();
            __builtin_amdgcn_sched_barrier(0);
            mm(3, afO, bfO);
        } else {
            waitcnt_lgkm<0>();
            __builtin_amdgcn_sched_barrier(0);
            mm(3, afO, bfO);
        }
    }

#pragma unroll
    for (int q = 0; q < 4; q++) {
#pragma unroll
        for (int m = 0; m < 4; m++) {
#pragma unroll
            for (int n = 0; n < 2; n++) {
                const long col  = bn + QN4[q] * 128 + wn2 * 32 + n * 16 + (lane & 15);
                const long row0 = bm + QM4[q] * 128 + wm2 * 64 + m * 16 + (lane >> 4) * 4;
#pragma unroll
                for (int j = 0; j < 4; j++) {
                    const long idx = (row0 + j) * (long)N + col;
                    ((short*)Cout)[idx] = f2b(acc[q][m][n][j]);
                }
            }
        }
    }
}

// ---------------------------------------------------------------------------
// NT GEMM, ring-2 double-buffer with COUNTED vmcnt (round-8 verified config)
// ---------------------------------------------------------------------------
template<int BM, int BN, int BK, int WR, int WC, int EPI, int SPLITK, int XSWZ>
__global__ __launch_bounds__(WR*WC*64, 2)
void gemm_ring(const short* __restrict__ A, const short* __restrict__ B,
               void* __restrict__ Cout, int M, int N, int K,
               const short* __restrict__ u_ptr)
{
    constexpr int MFR = BM / (WR * 16);
    constexpr int NFR = BN / (WC * 16);
    constexpr int THREADS = WR * WC * 64;
    constexpr int UPR = BK / 8;
    constexpr int AISS = (BM * UPR) / THREADS;
    constexpr int BISS = (BN * UPR) / THREADS;
    constexpr int LPS  = AISS + BISS;
    __shared__ __align__(16) short As[2][BM * BK];
    __shared__ __align__(16) short Bs[2][BN * BK];

    int bx = blockIdx.x, by = blockIdx.y;
    swz_block<XSWZ>(bx, by);

    const int tid  = threadIdx.x;
    const int lane = tid & 63;
    const int wave = tid >> 6;
    const int wm = (wave / WC) * (MFR * 16);
    const int wn = (wave % WC) * (NFR * 16);
    const long bm = (long)by * BM;
    const long bn = (long)bx * BN;

    f32x4v acc[MFR][NFR];
#pragma unroll
    for (int m = 0; m < MFR; m++)
#pragma unroll
        for (int n = 0; n < NFR; n++)
            acc[m][n] = (f32x4v){0.f, 0.f, 0.f, 0.f};

    const int rsel = lane & 15;
    const int ssrc = (((tid & 7) ^ ((tid >> 3) & 7)) * 8);
    const int swz  = lane & 7;

    int kbeg = 0, kend = K;
    if constexpr (SPLITK > 1) {
        const int kch = K / SPLITK;
        kbeg = blockIdx.z * kch;
        kend = kbeg + kch;
    }
    const int nt = (kend - kbeg) / BK;

    auto stage = [&](int buf, int k0) {
#pragma unroll
        for (int i = 0; i < AISS; i++) {
            const int j = i * THREADS + tid;
            gld_lds16(&As[buf][j * 8],
                      &A[(bm + (j >> 3)) * (long)K + k0 + ssrc]);
        }
#pragma unroll
        for (int i = 0; i < BISS; i++) {
            const int j = i * THREADS + tid;
            gld_lds16(&Bs[buf][j * 8],
                      &B[(bn + (j >> 3)) * (long)K + k0 + ssrc]);
        }
    };
    auto compute = [&](int buf) {
#pragma unroll
        for (int kk = 0; kk < BK; kk += 32) {
            const int slog = (kk >> 3) + (lane >> 4);
            const int soff = ((slog ^ swz) * 8);
            bf16x8v af[MFR], bfv[NFR];
#pragma unroll
            for (int m = 0; m < MFR; m++)
                af[m] = *(const bf16x8v*)&As[buf][(wm + m * 16 + rsel) * BK + soff];
#pragma unroll
            for (int n = 0; n < NFR; n++)
                bfv[n] = *(const bf16x8v*)&Bs[buf][(wn + n * 16 + rsel) * BK + soff];
#pragma unroll
            for (int m = 0; m < MFR; m++)
#pragma unroll
                for (int n = 0; n < NFR; n++)
                    acc[m][n] = __builtin_amdgcn_mfma_f32_16x16x32_bf16(
                        af[m], bfv[n], acc[m][n], 0, 0, 0);
        }
    };

    stage(0, kbeg);
    for (int t = 0; t < nt; ++t) {
        const bool pf = (t + 1 < nt);
        if (pf) stage((t + 1) & 1, kbeg + (t + 1) * BK);
        if (pf) waitcnt_vm<LPS>();
        else    waitcnt_vm<0>();
        block_barrier();
        compute(t & 1);
        block_barrier();
    }

    float* fout = (float*)Cout;
    if constexpr (SPLITK > 1)
        fout += (long)blockIdx.z * (long)M * N;

#pragma unroll
    for (int m = 0; m < MFR; m++) {
#pragma unroll
        for (int n = 0; n < NFR; n++) {
            const long col  = bn + wn + n * 16 + (lane & 15);
            const long row0 = bm + wm + m * 16 + (lane >> 4) * 4;
#pragma unroll
            for (int j = 0; j < 4; j++) {
                const long row = row0 + j;
                const float v = acc[m][n][j];
                const long idx = row * (long)N + col;
                if constexpr (EPI == 0) {
                    ((short*)Cout)[idx] = f2b(v);
                } else if constexpr (EPI == 1) {
                    fout[idx] = v;
                } else {   // EPI == 3: + residual x, store bf16
                    ((short*)Cout)[idx] = f2b(v + b2f(u_ptr[idx]));
                }
            }
        }
    }
}

// ---------------------------------------------------------------------------
// depthwise causal conv1d(k=4, left-pad 3) + bias + SiLU
// ---------------------------------------------------------------------------
__global__ __launch_bounds__(256)
void conv_silu_kernel(const short* __restrict__ xproj, const float* __restrict__ cw,
                      const float* __restrict__ cb, short* __restrict__ u)
{
    const int bt = blockIdx.x;
    const int t  = bt & (T_SEQ - 1);
    const int c0 = threadIdx.x * 8;

    float wreg[4][8];
#pragma unroll
    for (int i = 0; i < 8; i++) {
        float4 wv = *(const float4*)&cw[(c0 + i) * 4];
        wreg[0][i] = wv.x; wreg[1][i] = wv.y; wreg[2][i] = wv.z; wreg[3][i] = wv.w;
    }
    float acc[8];
#pragma unroll
    for (int i = 0; i < 8; i++) acc[i] = cb[c0 + i];

#pragma unroll
    for (int k = 0; k < 4; k++) {
        if (t - 3 + k < 0) continue;
        bf16x8v v = *(const bf16x8v*)&xproj[(long)(bt - 3 + k) * (2 * INNER) + c0];
#pragma unroll
        for (int i = 0; i < 8; i++) acc[i] += b2f(v[i]) * wreg[k][i];
    }
    short o[8];
#pragma unroll
    for (int i = 0; i < 8; i++) {
        float s = acc[i] / (1.f + __expf(-acc[i]));
        o[i] = f2b(s);
    }
    *(bf16x8v*)&u[(long)bt * INNER + c0] = *(const bf16x8v*)o;
}

// ---------------------------------------------------------------------------
// GEMM3 fused (K=64, nt=1): y = hs @ W_C^T; yg = (y + D*u) * silu(gate).
// ---------------------------------------------------------------------------
#define EBS 132
__global__ __launch_bounds__(256, 2)
void gemm3_fused(const short* __restrict__ hs, const short* __restrict__ Wc,
                 short* __restrict__ yg, const short* __restrict__ gate_ptr,
                 const float* __restrict__ Dp)
{
    __shared__ __align__(16) short As[128 * 64];
    __shared__ __align__(16) short Bs[128 * 64];
    __shared__ __align__(16) float eb[64 * EBS];

    const int tid  = threadIdx.x;
    const int lane = tid & 63;
    const int wave = tid >> 6;
    const int wm = (wave >> 1) * 64;
    const int wn = (wave & 1) * 64;
    const long bm = (long)blockIdx.y * 128;
    const long bn = (long)blockIdx.x * 128;

    const int rsel = lane & 15;
    const int ssrc = (((tid & 7) ^ ((tid >> 3) & 7)) * 8);
    const int swz  = lane & 7;

#pragma unroll
    for (int i = 0; i < 4; i++) {
        const int j = i * 256 + tid;
        gld_lds16(&As[j * 8], &hs[(bm + (j >> 3)) * (long)STATE + ssrc]);
    }
#pragma unroll
    for (int i = 0; i < 4; i++) {
        const int j = i * 256 + tid;
        gld_lds16(&Bs[j * 8], &Wc[(bn + (j >> 3)) * (long)STATE + ssrc]);
    }
    waitcnt_vm<0>();
    block_barrier();

    f32x4v acc[4][4];
#pragma unroll
    for (int m = 0; m < 4; m++)
#pragma unroll
        for (int n = 0; n < 4; n++)
            acc[m][n] = (f32x4v){0.f, 0.f, 0.f, 0.f};

#pragma unroll
    for (int kk = 0; kk < 64; kk += 32) {
        const int slog = (kk >> 3) + (lane >> 4);
        const int soff = ((slog ^ swz) * 8);
        bf16x8v af[4], bfv[4];
#pragma unroll
        for (int m = 0; m < 4; m++)
            af[m] = *(const bf16x8v*)&As[(wm + m * 16 + rsel) * 64 + soff];
#pragma unroll
        for (int n = 0; n < 4; n++)
            bfv[n] = *(const bf16x8v*)&Bs[(wn + n * 16 + rsel) * 64 + soff];
#pragma unroll
        for (int m = 0; m < 4; m++)
#pragma unroll
            for (int n = 0; n < 4; n++)
                acc[m][n] = __builtin_amdgcn_mfma_f32_16x16x32_bf16(
                    af[m], bfv[n], acc[m][n], 0, 0, 0);
    }

#pragma unroll
    for (int p = 0; p < 2; p++) {
        block_barrier();
        if ((wm >> 6) == p) {
#pragma unroll
            for (int m = 0; m < 4; m++) {
#pragma unroll
                for (int n = 0; n < 4; n++) {
                    const int cl = wn + n * 16 + (lane & 15);
#pragma unroll
                    for (int j = 0; j < 4; j++) {
                        const int rl = m * 16 + (lane >> 4) * 4 + j;
                        eb[rl * EBS + cl] = acc[m][n][j];
                    }
                }
            }
        }
        block_barrier();
#pragma unroll
        for (int k = 0; k < 4; k++) {
            const int unit = k * 256 + tid;
            const int rl = unit >> 4, cg = (unit & 15) * 8;
            const long grow = bm + p * 64 + rl;
            const long gcol = bn + cg;
            f32x4v y0 = *(const f32x4v*)&eb[rl * EBS + cg];
            f32x4v y1 = *(const f32x4v*)&eb[rl * EBS + cg + 4];
            bf16x8v uv = *(const bf16x8v*)&yg[grow * (long)INNER + gcol];
            bf16x8v gv = *(const bf16x8v*)&gate_ptr[grow * (long)(2 * INNER) + gcol];
            short o[8];
#pragma unroll
            for (int i = 0; i < 8; i++) {
                const float yy = (i < 4 ? y0[i] : y1[i - 4]);
                const float uu = b2f(uv[i]);
                const float gg = b2f(gv[i]);
                const float yv = yy + Dp[gcol + i] * uu;
                const float sg = gg / (1.f + __expf(-gg));
                o[i] = f2b(yv * sg);
            }
            *(bf16x8v*)&yg[grow * (long)INNER + gcol] = *(const bf16x8v*)o;
        }
    }
}

// ---------------------------------------------------------------------------
// Chunked parallel scan; Bu given as 4 split-K partials (stride PSTRIDE)
// (round-13 proven 3-kernel form)
// ---------------------------------------------------------------------------
__global__ __launch_bounds__(64)
void scan_local_kernel(const float* __restrict__ Bu, float* __restrict__ locfin)
{
    const int b  = blockIdx.x / NCHUNK;
    const int ch = blockIdx.x % NCHUNK;
    const long base = ((long)b * T_SEQ + (long)ch * CHUNK_L) * STATE + threadIdx.x;
    float h = 0.f;
#pragma unroll
    for (int t = 0; t < CHUNK_L; t++) {
        const long o = base + (long)t * STATE;
        float bu = (Bu[o] + Bu[o + PSTRIDE]) + (Bu[o + 2 * PSTRIDE] + Bu[o + 3 * PSTRIDE]);
        h = 0.95f * h + 0.05f * bu;
    }
    locfin[(long)blockIdx.x * STATE + threadIdx.x] = h;
}

__global__ __launch_bounds__(256)
void carry_kernel(const float* __restrict__ locfin, float* __restrict__ carry,
                  float decayL)
{
    __shared__ float sm[BATCH * NCHUNK * STATE];
    for (int i = threadIdx.x; i < BATCH * NCHUNK * STATE; i += 256)
        sm[i] = locfin[i];
    __syncthreads();
    const int b = threadIdx.x >> 6, s = threadIdx.x & 63;
    float c = 0.f;
    for (int ch = 0; ch < NCHUNK; ch++) {
        const int idx = (b * NCHUNK + ch) * STATE + s;
        carry[idx] = c;
        c = decayL * c + sm[idx];
    }
}

__global__ __launch_bounds__(64)
void scan_apply_kernel(const float* __restrict__ Bu, const float* __restrict__ carry,
                       short* __restrict__ hs)
{
    const int b  = blockIdx.x / NCHUNK;
    const int ch = blockIdx.x % NCHUNK;
    const long base = ((long)b * T_SEQ + (long)ch * CHUNK_L) * STATE + threadIdx.x;
    float h = carry[(long)blockIdx.x * STATE + threadIdx.x];
#pragma unroll
    for (int t = 0; t < CHUNK_L; t++) {
        const long o = base + (long)t * STATE;
        float bu = (Bu[o] + Bu[o + PSTRIDE]) + (Bu[o + 2 * PSTRIDE] + Bu[o + 3 * PSTRIDE]);
        h = 0.95f * h + 0.05f * bu;
        hs[o] = f2b(h);
    }
}

// ---------------------------------------------------------------------------
// LayerNorm over pre-summed bf16 (y + x) -> out (f32)
// ---------------------------------------------------------------------------
__global__ __launch_bounds__(256)
void ln_kernel(const short* __restrict__ yx, const float* __restrict__ g,
               const float* __restrict__ b, float* __restrict__ out)
{
    const int row = blockIdx.x;
    const int c   = threadIdx.x * 4;
    const long off = (long)row * DIMD + c;
    const short4v yv = *(const short4v*)&yx[off];
    float s0 = b2f(yv[0]), s1 = b2f(yv[1]), s2 = b2f(yv[2]), s3 = b2f(yv[3]);
    float sum = s0 + s1 + s2 + s3;
    float sq  = s0 * s0 + s1 * s1 + s2 * s2 + s3 * s3;
#pragma unroll
    for (int o = 32; o > 0; o >>= 1) {
        sum += __shfl_down(sum, o);
        sq  += __shfl_down(sq, o);
    }
    __shared__ float rs[4], rq[4];
    const int wave = threadIdx.x >> 6, lane = threadIdx.x & 63;
    if (lane == 0) { rs[wave] = sum; rq[wave] = sq; }
    __syncthreads();
    float tsum = rs[0] + rs[1] + rs[2] + rs[3];
    float tsq  = rq[0] + rq[1] + rq[2] + rq[3];
    float mu  = tsum * (1.f / DIMD);
    float inv = rsqrtf(tsq * (1.f / DIMD) - mu * mu + 1e-5f);
    float4 gv = *(const float4*)&g[c];
    float4 bv = *(const float4*)&b[c];
    float4 ov;
    ov.x = (s0 - mu) * inv * gv.x + bv.x;
    ov.y = (s1 - mu) * inv * gv.y + bv.y;
    ov.z = (s2 - mu) * inv * gv.z + bv.z;
    ov.w = (s3 - mu) * inv * gv.w + bv.w;
    *(float4*)&out[off] = ov;
}

// ---------------------------------------------------------------------------
// fused f32->bf16 convert of all 5 tensors into the contiguous ws region
// ---------------------------------------------------------------------------
#define C4_X   2097152L
#define C4_W1  (C4_X + 1048576L)
#define C4_WB  (C4_W1 + 32768L)
#define C4_WC  (C4_WB + 32768L)
#define C4_TOT (C4_WC + 524288L)

__global__ __launch_bounds__(256)
void cvt5_kernel(const float* __restrict__ x, const float* __restrict__ w1,
                 const float* __restrict__ wB, const float* __restrict__ wC,
                 const float* __restrict__ wO, short* __restrict__ dst)
{
    const long i = (long)blockIdx.x * 256 + threadIdx.x;
    if (i >= C4_TOT) return;
    const float* s;
    long off;
    if      (i < C4_X)  { s = x;  off = i; }
    else if (i < C4_W1) { s = w1; off = i - C4_X; }
    else if (i < C4_WB) { s = wB; off = i - C4_W1; }
    else if (i < C4_WC) { s = wC; off = i - C4_WB; }
    else                { s = wO; off = i - C4_WC; }
    float4 v = *(const float4*)&s[off * 4];
    short4v o = { f2b(v.x), f2b(v.y), f2b(v.z), f2b(v.w) };
    *(short4v*)&dst[i * 4] = o;
}

extern "C" void kernel_launch(void* const* d_in, const int* in_sizes, int n_in,
                              void* d_out, int out_size, void* d_ws, size_t ws_size,
                              hipStream_t stream)
{
    const float* x     = (const float*)d_in[0];
    const float* W_in  = (const float*)d_in[1];
    const float* cw    = (const float*)d_in[2];
    const float* cb    = (const float*)d_in[3];
    const float* W_B   = (const float*)d_in[4];
    const float* W_C   = (const float*)d_in[5];
    const float* Dp    = (const float*)d_in[6];
    const float* W_out = (const float*)d_in[7];
    const float* ln_g  = (const float*)d_in[8];
    const float* ln_b  = (const float*)d_in[9];

    // workspace layout (bytes). total: 133,693,440 (~128 MB)
    char* p = (char*)d_ws;
    short* xw    = (short*)(p);                 // x bf16 [8192,1024] — LIVE until GEMM4
    short* w1    = (short*)(p +  16777216);     // W_in bf16 — dead after GEMM1
    short* wB    = (short*)(p +  25165824);     // W_B bf16  — dead after GEMM2
    short* wC    = (short*)(p +  25427968);     // W_C bf16  — read by GEMM3
    short* wO    = (short*)(p +  25690112);     // W_out bf16 — read by GEMM4
    short* xproj = (short*)(p +  29884416);     // x_proj bf16 [8192,4096]
    short* u     = (short*)(p +  96993280);     // u bf16 [8192,2048]
    short* hs    = (short*)(p + 132644864);     // hs bf16 [8192,64]
    short* yg    = u;                           // alias: in-place GEMM3 epilogue
    short* yx    = xproj;                       // GEMM4 out bf16(y+x), over dead xproj
    // scan/split-K scratch in DEAD regions (xw survives for GEMM4 EPI=3):
    float* BuP    = (float*)(p + 16777216);     // 4x [8192,64] f32 = 8,388,608 (w1)
    float* locfin = (float*)(p + 25165824);     // 65,536 (wB region, dead post-GEMM2)
    float* carry  = (float*)(p + 25231360);     // 65,536

    const int M = MROWS;  // 8192

    cvt5_kernel<<<(int)((C4_TOT + 255) / 256), 256, 0, stream>>>(
        x, W_in, W_B, W_C, W_out, xw);

    // GEMM1: x_proj = x @ W_in^T  [8192,4096] bf16 — reg-dbuf 8-phase + region swz
    gemm_8ph<0, 2><<<dim3(2 * INNER / 256, M / 256), 512, 0, stream>>>(
        xw, w1, xproj, M, 2 * INNER, DIMD);

    // conv + silu -> u
    conv_silu_kernel<<<M, 256, 0, stream>>>(xproj, cw, cb, u);

    // GEMM2: BuP[z] = u @ W_B^T partials  [4][8192, 64] f32 (split-K x4)
    gemm_ring<64, 64, 64, 2, 2, 1, 4, 0><<<dim3(1, M / 64, 4), 256, 0, stream>>>(
        u, wB, BuP, M, STATE, INNER, nullptr);

    // chunked parallel scan -> hs (bf16); sums the 4 partials on load
    float decayL;
    {
        double dd = 1.0;
        for (int i = 0; i < CHUNK_L; i++) dd *= 0.95;
        decayL = (float)dd;
    }
    scan_local_kernel<<<BATCH * NCHUNK, STATE, 0, stream>>>(BuP, locfin);
    carry_kernel<<<1, 256, 0, stream>>>(locfin, carry, decayL);
    scan_apply_kernel<<<BATCH * NCHUNK, STATE, 0, stream>>>(BuP, carry, hs);

    // GEMM3 fused: yg = (hs @ W_C^T + D*u) * silu(gate)  [8192, 2048] bf16
    gemm3_fused<<<dim3(INNER / 128, M / 128), 256, 0, stream>>>(
        hs, wC, yg, xproj + INNER, Dp);

    // GEMM4: yx = bf16(yg @ W_out^T + x)  [8192,1024] — round-8 proven config
    gemm_ring<128, 128, 64, 2, 2, 3, 1, 1><<<dim3(DIMD / 128, M / 128), 256, 0, stream>>>(
        yg, wO, yx, M, DIMD, INNER, xw);

    // LayerNorm(yx) -> d_out
    ln_kernel<<<M, 256, 0, stream>>>(yx, ln_g, ln_b, (float*)d_out);
}

// Round 18
// 242.016 us; speedup vs baseline: 1.4026x; 1.4026x over previous
//
#include <hip/hip_runtime.h>
#include <hip/hip_bf16.h>

#define T_SEQ 2048
#define DIMD  1024
#define INNER 2048
#define STATE 64
#define BATCH 4
#define NCHUNK 64
#define CHUNK_L (T_SEQ / NCHUNK)   // 32
#define MROWS (BATCH * T_SEQ)      // 8192
#define PSTRIDE ((long)MROWS * STATE)

typedef __hip_bfloat16 bf16;
typedef __attribute__((ext_vector_type(8))) short bf16x8v;
typedef __attribute__((ext_vector_type(4))) float f32x4v;
typedef __attribute__((ext_vector_type(4))) short short4v;

__device__ __forceinline__ float b2f(short s) {
    unsigned u = ((unsigned)(unsigned short)s) << 16;
    float f;
    __builtin_memcpy(&f, &u, 4);
    return f;
}
__device__ __forceinline__ short f2b(float f) {
    bf16 h = __float2bfloat16(f);  // RNE
    short s;
    __builtin_memcpy(&s, &h, 2);
    return s;
}

// async global->LDS, 16B per lane. LDS dest must be lane-linear.
__device__ __forceinline__ void gld_lds16(void* lds, const void* gsrc) {
    __builtin_amdgcn_global_load_lds(
        (const __attribute__((address_space(1))) unsigned*)gsrc,
        (__attribute__((address_space(3))) unsigned*)lds, 16, 0, 0);
}

template<int N> __device__ __forceinline__ void waitcnt_vm() {
    if constexpr (N == 8)       asm volatile("s_waitcnt vmcnt(8)" ::: "memory");
    else if constexpr (N == 4)  asm volatile("s_waitcnt vmcnt(4)" ::: "memory");
    else if constexpr (N == 2)  asm volatile("s_waitcnt vmcnt(2)" ::: "memory");
    else                        asm volatile("s_waitcnt vmcnt(0)" ::: "memory");
}
__device__ __forceinline__ void block_barrier() {
    asm volatile("" ::: "memory");
    __builtin_amdgcn_s_barrier();
    asm volatile("" ::: "memory");
}

// Block swizzle. Mode 1: XCD contiguous-chunk (nwg%8==0). Mode 2: region
// (4x4 blocks per region within an XCD strip; L2-resident panel sharing).
template<int XSWZ>
__device__ __forceinline__ void swz_block(int& bx, int& by) {
    if constexpr (XSWZ == 1) {
        const int gx = gridDim.x;
        const int nwg = gx * gridDim.y;
        int id = by * gx + bx;
        const int cpx = nwg >> 3;
        id = (id & 7) * cpx + (id >> 3);
        bx = id % gx; by = id / gx;
    } else if constexpr (XSWZ == 2) {
        const int gx = gridDim.x;
        const int gy = gridDim.y;
        const int id = by * gx + bx;
        const int xcd = id & 7;
        const int c   = id >> 3;
        const int rowsX = gy >> 3;
        const int rw  = gx >> 2;
        const int r   = c >> 4;
        const int pos = c & 15;
        const int rbx = (r % rw) << 2;
        const int rby = (r / rw) << 2;
        bx = rbx + (pos & 3);
        by = xcd * rowsX + rby + (pos >> 2);
    }
}

// ---------------------------------------------------------------------------
// 8-phase 256^2 GEMM — round-13 WINNER: depth-3 counted vmcnt at phase TOP,
// one barrier per phase. (Session optimum; 6 schedule variants all <= this.)
// ---------------------------------------------------------------------------
template<int EPI, int XSWZ>
__global__ __launch_bounds__(512, 2)
void gemm_8ph(const short* __restrict__ A, const short* __restrict__ B,
              void* __restrict__ Cout, int M, int N, int K)
{
    __shared__ __align__(16) short As[2][2][128 * 64];
    __shared__ __align__(16) short Bs[2][2][128 * 64];

    int bx = blockIdx.x, by = blockIdx.y;
    swz_block<XSWZ>(bx, by);

    const int tid  = threadIdx.x;
    const int lane = tid & 63;
    const int wave = tid >> 6;
    const int wm2 = (wave >> 2) & 1;
    const int wn2 = wave & 3;
    const long bm = (long)by * 256;
    const long bn = (long)bx * 256;

    const int rsel = lane & 15;
    const int ssrc = (((tid & 7) ^ ((tid >> 3) & 7)) * 8);
    const int swz  = lane & 7;

    f32x4v acc[4][4][2];
#pragma unroll
    for (int q = 0; q < 4; q++)
#pragma unroll
        for (int m = 0; m < 4; m++)
#pragma unroll
            for (int n = 0; n < 2; n++)
                acc[q][m][n] = (f32x4v){0.f, 0.f, 0.f, 0.f};

    const int nt = K / 64;

    auto stage_half = [&](int tt, int h) {
        const int buf = tt & 1;
        const int half = h >> 1;
        const int k0 = tt * 64;
#pragma unroll
        for (int i = 0; i < 2; i++) {
            const int j = i * 512 + tid;
            if (h & 1)
                gld_lds16(&Bs[buf][half][j * 8],
                          &B[(bn + half * 128 + (j >> 3)) * (long)K + k0 + ssrc]);
            else
                gld_lds16(&As[buf][half][j * 8],
                          &A[(bm + half * 128 + (j >> 3)) * (long)K + k0 + ssrc]);
        }
    };

    stage_half(0, 0); stage_half(0, 1); stage_half(0, 2); stage_half(0, 3);

    for (int t = 0; t < nt; ++t) {
        const int buf = t & 1;
        const bool pf = (t + 1 < nt);
#pragma unroll
        for (int h = 0; h < 4; ++h) {
            if (pf) {
                if (h < 3) waitcnt_vm<4>();
            } else {
                if (h == 0) waitcnt_vm<4>();
                else if (h == 1) waitcnt_vm<2>();
                else if (h == 2) waitcnt_vm<0>();
            }
            block_barrier();

            const int QM[4] = {0, 1, 1, 0};
            const int QN[4] = {0, 0, 1, 1};
            const int qm = QM[h], qn = QN[h];
            bf16x8v af[4][2], bfv[2][2];
#pragma unroll
            for (int kkh = 0; kkh < 2; kkh++) {
                const int slog = kkh * 4 + (lane >> 4);
                const int soff = ((slog ^ swz) * 8);
#pragma unroll
                for (int m = 0; m < 4; m++) {
                    const int ar = wm2 * 64 + m * 16 + rsel;
                    af[m][kkh] = *(const bf16x8v*)&As[buf][qm][ar * 64 + soff];
                }
#pragma unroll
                for (int n = 0; n < 2; n++) {
                    const int br = wn2 * 32 + n * 16 + rsel;
                    bfv[n][kkh] = *(const bf16x8v*)&Bs[buf][qn][br * 64 + soff];
                }
            }
            if (pf) stage_half(t + 1, h);

            asm volatile("s_waitcnt lgkmcnt(0)" ::: "memory");
            __builtin_amdgcn_sched_barrier(0);
            __builtin_amdgcn_s_setprio(1);
#pragma unroll
            for (int kkh = 0; kkh < 2; kkh++)
#pragma unroll
                for (int m = 0; m < 4; m++)
#pragma unroll
                    for (int n = 0; n < 2; n++)
                        acc[h][m][n] = __builtin_amdgcn_mfma_f32_16x16x32_bf16(
                            af[m][kkh], bfv[n][kkh], acc[h][m][n], 0, 0, 0);
            __builtin_amdgcn_s_setprio(0);
        }
    }

#pragma unroll
    for (int q = 0; q < 4; q++) {
        const int QM[4] = {0, 1, 1, 0};
        const int QN[4] = {0, 0, 1, 1};
#pragma unroll
        for (int m = 0; m < 4; m++) {
#pragma unroll
            for (int n = 0; n < 2; n++) {
                const long col  = bn + QN[q] * 128 + wn2 * 32 + n * 16 + (lane & 15);
                const long row0 = bm + QM[q] * 128 + wm2 * 64 + m * 16 + (lane >> 4) * 4;
#pragma unroll
                for (int j = 0; j < 4; j++) {
                    const long idx = (row0 + j) * (long)N + col;
                    ((short*)Cout)[idx] = f2b(acc[q][m][n][j]);
                }
            }
        }
    }
}

// ---------------------------------------------------------------------------
// NT GEMM, ring-2 double-buffer with COUNTED vmcnt (round-8 verified config)
// ---------------------------------------------------------------------------
template<int BM, int BN, int BK, int WR, int WC, int EPI, int SPLITK, int XSWZ>
__global__ __launch_bounds__(WR*WC*64, 2)
void gemm_ring(const short* __restrict__ A, const short* __restrict__ B,
               void* __restrict__ Cout, int M, int N, int K,
               const short* __restrict__ u_ptr)
{
    constexpr int MFR = BM / (WR * 16);
    constexpr int NFR = BN / (WC * 16);
    constexpr int THREADS = WR * WC * 64;
    constexpr int UPR = BK / 8;
    constexpr int AISS = (BM * UPR) / THREADS;
    constexpr int BISS = (BN * UPR) / THREADS;
    constexpr int LPS  = AISS + BISS;
    __shared__ __align__(16) short As[2][BM * BK];
    __shared__ __align__(16) short Bs[2][BN * BK];

    int bx = blockIdx.x, by = blockIdx.y;
    swz_block<XSWZ>(bx, by);

    const int tid  = threadIdx.x;
    const int lane = tid & 63;
    const int wave = tid >> 6;
    const int wm = (wave / WC) * (MFR * 16);
    const int wn = (wave % WC) * (NFR * 16);
    const long bm = (long)by * BM;
    const long bn = (long)bx * BN;

    f32x4v acc[MFR][NFR];
#pragma unroll
    for (int m = 0; m < MFR; m++)
#pragma unroll
        for (int n = 0; n < NFR; n++)
            acc[m][n] = (f32x4v){0.f, 0.f, 0.f, 0.f};

    const int rsel = lane & 15;
    const int ssrc = (((tid & 7) ^ ((tid >> 3) & 7)) * 8);
    const int swz  = lane & 7;

    int kbeg = 0, kend = K;
    if constexpr (SPLITK > 1) {
        const int kch = K / SPLITK;
        kbeg = blockIdx.z * kch;
        kend = kbeg + kch;
    }
    const int nt = (kend - kbeg) / BK;

    auto stage = [&](int buf, int k0) {
#pragma unroll
        for (int i = 0; i < AISS; i++) {
            const int j = i * THREADS + tid;
            gld_lds16(&As[buf][j * 8],
                      &A[(bm + (j >> 3)) * (long)K + k0 + ssrc]);
        }
#pragma unroll
        for (int i = 0; i < BISS; i++) {
            const int j = i * THREADS + tid;
            gld_lds16(&Bs[buf][j * 8],
                      &B[(bn + (j >> 3)) * (long)K + k0 + ssrc]);
        }
    };
    auto compute = [&](int buf) {
#pragma unroll
        for (int kk = 0; kk < BK; kk += 32) {
            const int slog = (kk >> 3) + (lane >> 4);
            const int soff = ((slog ^ swz) * 8);
            bf16x8v af[MFR], bfv[NFR];
#pragma unroll
            for (int m = 0; m < MFR; m++)
                af[m] = *(const bf16x8v*)&As[buf][(wm + m * 16 + rsel) * BK + soff];
#pragma unroll
            for (int n = 0; n < NFR; n++)
                bfv[n] = *(const bf16x8v*)&Bs[buf][(wn + n * 16 + rsel) * BK + soff];
#pragma unroll
            for (int m = 0; m < MFR; m++)
#pragma unroll
                for (int n = 0; n < NFR; n++)
                    acc[m][n] = __builtin_amdgcn_mfma_f32_16x16x32_bf16(
                        af[m], bfv[n], acc[m][n], 0, 0, 0);
        }
    };

    stage(0, kbeg);
    for (int t = 0; t < nt; ++t) {
        const bool pf = (t + 1 < nt);
        if (pf) stage((t + 1) & 1, kbeg + (t + 1) * BK);
        if (pf) waitcnt_vm<LPS>();
        else    waitcnt_vm<0>();
        block_barrier();
        compute(t & 1);
        block_barrier();
    }

    float* fout = (float*)Cout;
    if constexpr (SPLITK > 1)
        fout += (long)blockIdx.z * (long)M * N;

#pragma unroll
    for (int m = 0; m < MFR; m++) {
#pragma unroll
        for (int n = 0; n < NFR; n++) {
            const long col  = bn + wn + n * 16 + (lane & 15);
            const long row0 = bm + wm + m * 16 + (lane >> 4) * 4;
#pragma unroll
            for (int j = 0; j < 4; j++) {
                const long row = row0 + j;
                const float v = acc[m][n][j];
                const long idx = row * (long)N + col;
                if constexpr (EPI == 0) {
                    ((short*)Cout)[idx] = f2b(v);
                } else if constexpr (EPI == 1) {
                    fout[idx] = v;
                } else {   // EPI == 3: + residual x, store bf16
                    ((short*)Cout)[idx] = f2b(v + b2f(u_ptr[idx]));
                }
            }
        }
    }
}

// ---------------------------------------------------------------------------
// depthwise causal conv1d(k=4, left-pad 3) + bias + SiLU
// ---------------------------------------------------------------------------
__global__ __launch_bounds__(256)
void conv_silu_kernel(const short* __restrict__ xproj, const float* __restrict__ cw,
                      const float* __restrict__ cb, short* __restrict__ u)
{
    const int bt = blockIdx.x;
    const int t  = bt & (T_SEQ - 1);
    const int c0 = threadIdx.x * 8;

    float wreg[4][8];
#pragma unroll
    for (int i = 0; i < 8; i++) {
        float4 wv = *(const float4*)&cw[(c0 + i) * 4];
        wreg[0][i] = wv.x; wreg[1][i] = wv.y; wreg[2][i] = wv.z; wreg[3][i] = wv.w;
    }
    float acc[8];
#pragma unroll
    for (int i = 0; i < 8; i++) acc[i] = cb[c0 + i];

#pragma unroll
    for (int k = 0; k < 4; k++) {
        if (t - 3 + k < 0) continue;
        bf16x8v v = *(const bf16x8v*)&xproj[(long)(bt - 3 + k) * (2 * INNER) + c0];
#pragma unroll
        for (int i = 0; i < 8; i++) acc[i] += b2f(v[i]) * wreg[k][i];
    }
    short o[8];
#pragma unroll
    for (int i = 0; i < 8; i++) {
        float s = acc[i] / (1.f + __expf(-acc[i]));
        o[i] = f2b(s);
    }
    *(bf16x8v*)&u[(long)bt * INNER + c0] = *(const bf16x8v*)o;
}

// ---------------------------------------------------------------------------
// GEMM3 fused (K=64, nt=1): y = hs @ W_C^T; yg = (y + D*u) * silu(gate).
// ---------------------------------------------------------------------------
#define EBS 132
__global__ __launch_bounds__(256, 2)
void gemm3_fused(const short* __restrict__ hs, const short* __restrict__ Wc,
                 short* __restrict__ yg, const short* __restrict__ gate_ptr,
                 const float* __restrict__ Dp)
{
    __shared__ __align__(16) short As[128 * 64];
    __shared__ __align__(16) short Bs[128 * 64];
    __shared__ __align__(16) float eb[64 * EBS];

    const int tid  = threadIdx.x;
    const int lane = tid & 63;
    const int wave = tid >> 6;
    const int wm = (wave >> 1) * 64;
    const int wn = (wave & 1) * 64;
    const long bm = (long)blockIdx.y * 128;
    const long bn = (long)blockIdx.x * 128;

    const int rsel = lane & 15;
    const int ssrc = (((tid & 7) ^ ((tid >> 3) & 7)) * 8);
    const int swz  = lane & 7;

#pragma unroll
    for (int i = 0; i < 4; i++) {
        const int j = i * 256 + tid;
        gld_lds16(&As[j * 8], &hs[(bm + (j >> 3)) * (long)STATE + ssrc]);
    }
#pragma unroll
    for (int i = 0; i < 4; i++) {
        const int j = i * 256 + tid;
        gld_lds16(&Bs[j * 8], &Wc[(bn + (j >> 3)) * (long)STATE + ssrc]);
    }
    waitcnt_vm<0>();
    block_barrier();

    f32x4v acc[4][4];
#pragma unroll
    for (int m = 0; m < 4; m++)
#pragma unroll
        for (int n = 0; n < 4; n++)
            acc[m][n] = (f32x4v){0.f, 0.f, 0.f, 0.f};

#pragma unroll
    for (int kk = 0; kk < 64; kk += 32) {
        const int slog = (kk >> 3) + (lane >> 4);
        const int soff = ((slog ^ swz) * 8);
        bf16x8v af[4], bfv[4];
#pragma unroll
        for (int m = 0; m < 4; m++)
            af[m] = *(const bf16x8v*)&As[(wm + m * 16 + rsel) * 64 + soff];
#pragma unroll
        for (int n = 0; n < 4; n++)
            bfv[n] = *(const bf16x8v*)&Bs[(wn + n * 16 + rsel) * 64 + soff];
#pragma unroll
        for (int m = 0; m < 4; m++)
#pragma unroll
            for (int n = 0; n < 4; n++)
                acc[m][n] = __builtin_amdgcn_mfma_f32_16x16x32_bf16(
                    af[m], bfv[n], acc[m][n], 0, 0, 0);
    }

#pragma unroll
    for (int p = 0; p < 2; p++) {
        block_barrier();
        if ((wm >> 6) == p) {
#pragma unroll
            for (int m = 0; m < 4; m++) {
#pragma unroll
                for (int n = 0; n < 4; n++) {
                    const int cl = wn + n * 16 + (lane & 15);
#pragma unroll
                    for (int j = 0; j < 4; j++) {
                        const int rl = m * 16 + (lane >> 4) * 4 + j;
                        eb[rl * EBS + cl] = acc[m][n][j];
                    }
                }
            }
        }
        block_barrier();
#pragma unroll
        for (int k = 0; k < 4; k++) {
            const int unit = k * 256 + tid;
            const int rl = unit >> 4, cg = (unit & 15) * 8;
            const long grow = bm + p * 64 + rl;
            const long gcol = bn + cg;
            f32x4v y0 = *(const f32x4v*)&eb[rl * EBS + cg];
            f32x4v y1 = *(const f32x4v*)&eb[rl * EBS + cg + 4];
            bf16x8v uv = *(const bf16x8v*)&yg[grow * (long)INNER + gcol];
            bf16x8v gv = *(const bf16x8v*)&gate_ptr[grow * (long)(2 * INNER) + gcol];
            short o[8];
#pragma unroll
            for (int i = 0; i < 8; i++) {
                const float yy = (i < 4 ? y0[i] : y1[i - 4]);
                const float uu = b2f(uv[i]);
                const float gg = b2f(gv[i]);
                const float yv = yy + Dp[gcol + i] * uu;
                const float sg = gg / (1.f + __expf(-gg));
                o[i] = f2b(yv * sg);
            }
            *(bf16x8v*)&yg[grow * (long)INNER + gcol] = *(const bf16x8v*)o;
        }
    }
}

// ---------------------------------------------------------------------------
// Chunked parallel scan; Bu given as 4 split-K partials (stride PSTRIDE)
// ---------------------------------------------------------------------------
__global__ __launch_bounds__(64)
void scan_local_kernel(const float* __restrict__ Bu, float* __restrict__ locfin)
{
    const int b  = blockIdx.x / NCHUNK;
    const int ch = blockIdx.x % NCHUNK;
    const long base = ((long)b * T_SEQ + (long)ch * CHUNK_L) * STATE + threadIdx.x;
    float h = 0.f;
#pragma unroll
    for (int t = 0; t < CHUNK_L; t++) {
        const long o = base + (long)t * STATE;
        float bu = (Bu[o] + Bu[o + PSTRIDE]) + (Bu[o + 2 * PSTRIDE] + Bu[o + 3 * PSTRIDE]);
        h = 0.95f * h + 0.05f * bu;
    }
    locfin[(long)blockIdx.x * STATE + threadIdx.x] = h;
}

__global__ __launch_bounds__(256)
void carry_kernel(const float* __restrict__ locfin, float* __restrict__ carry,
                  float decayL)
{
    __shared__ float sm[BATCH * NCHUNK * STATE];
    for (int i = threadIdx.x; i < BATCH * NCHUNK * STATE; i += 256)
        sm[i] = locfin[i];
    __syncthreads();
    const int b = threadIdx.x >> 6, s = threadIdx.x & 63;
    float c = 0.f;
    for (int ch = 0; ch < NCHUNK; ch++) {
        const int idx = (b * NCHUNK + ch) * STATE + s;
        carry[idx] = c;
        c = decayL * c + sm[idx];
    }
}

__global__ __launch_bounds__(64)
void scan_apply_kernel(const float* __restrict__ Bu, const float* __restrict__ carry,
                       short* __restrict__ hs)
{
    const int b  = blockIdx.x / NCHUNK;
    const int ch = blockIdx.x % NCHUNK;
    const long base = ((long)b * T_SEQ + (long)ch * CHUNK_L) * STATE + threadIdx.x;
    float h = carry[(long)blockIdx.x * STATE + threadIdx.x];
#pragma unroll
    for (int t = 0; t < CHUNK_L; t++) {
        const long o = base + (long)t * STATE;
        float bu = (Bu[o] + Bu[o + PSTRIDE]) + (Bu[o + 2 * PSTRIDE] + Bu[o + 3 * PSTRIDE]);
        h = 0.95f * h + 0.05f * bu;
        hs[o] = f2b(h);
    }
}

// ---------------------------------------------------------------------------
// LayerNorm over pre-summed bf16 (y + x) -> out (f32)
// ---------------------------------------------------------------------------
__global__ __launch_bounds__(256)
void ln_kernel(const short* __restrict__ yx, const float* __restrict__ g,
               const float* __restrict__ b, float* __restrict__ out)
{
    const int row = blockIdx.x;
    const int c   = threadIdx.x * 4;
    const long off = (long)row * DIMD + c;
    const short4v yv = *(const short4v*)&yx[off];
    float s0 = b2f(yv[0]), s1 = b2f(yv[1]), s2 = b2f(yv[2]), s3 = b2f(yv[3]);
    float sum = s0 + s1 + s2 + s3;
    float sq  = s0 * s0 + s1 * s1 + s2 * s2 + s3 * s3;
#pragma unroll
    for (int o = 32; o > 0; o >>= 1) {
        sum += __shfl_down(sum, o);
        sq  += __shfl_down(sq, o);
    }
    __shared__ float rs[4], rq[4];
    const int wave = threadIdx.x >> 6, lane = threadIdx.x & 63;
    if (lane == 0) { rs[wave] = sum; rq[wave] = sq; }
    __syncthreads();
    float tsum = rs[0] + rs[1] + rs[2] + rs[3];
    float tsq  = rq[0] + rq[1] + rq[2] + rq[3];
    float mu  = tsum * (1.f / DIMD);
    float inv = rsqrtf(tsq * (1.f / DIMD) - mu * mu + 1e-5f);
    float4 gv = *(const float4*)&g[c];
    float4 bv = *(const float4*)&b[c];
    float4 ov;
    ov.x = (s0 - mu) * inv * gv.x + bv.x;
    ov.y = (s1 - mu) * inv * gv.y + bv.y;
    ov.z = (s2 - mu) * inv * gv.z + bv.z;
    ov.w = (s3 - mu) * inv * gv.w + bv.w;
    *(float4*)&out[off] = ov;
}

// ---------------------------------------------------------------------------
// fused f32->bf16 convert of all 5 tensors into the contiguous ws region
// ---------------------------------------------------------------------------
#define C4_X   2097152L
#define C4_W1  (C4_X + 1048576L)
#define C4_WB  (C4_W1 + 32768L)
#define C4_WC  (C4_WB + 32768L)
#define C4_TOT (C4_WC + 524288L)

__global__ __launch_bounds__(256)
void cvt5_kernel(const float* __restrict__ x, const float* __restrict__ w1,
                 const float* __restrict__ wB, const float* __restrict__ wC,
                 const float* __restrict__ wO, short* __restrict__ dst)
{
    const long i = (long)blockIdx.x * 256 + threadIdx.x;
    if (i >= C4_TOT) return;
    const float* s;
    long off;
    if      (i < C4_X)  { s = x;  off = i; }
    else if (i < C4_W1) { s = w1; off = i - C4_X; }
    else if (i < C4_WB) { s = wB; off = i - C4_W1; }
    else if (i < C4_WC) { s = wC; off = i - C4_WB; }
    else                { s = wO; off = i - C4_WC; }
    float4 v = *(const float4*)&s[off * 4];
    short4v o = { f2b(v.x), f2b(v.y), f2b(v.z), f2b(v.w) };
    *(short4v*)&dst[i * 4] = o;
}

extern "C" void kernel_launch(void* const* d_in, const int* in_sizes, int n_in,
                              void* d_out, int out_size, void* d_ws, size_t ws_size,
                              hipStream_t stream)
{
    const float* x     = (const float*)d_in[0];
    const float* W_in  = (const float*)d_in[1];
    const float* cw    = (const float*)d_in[2];
    const float* cb    = (const float*)d_in[3];
    const float* W_B   = (const float*)d_in[4];
    const float* W_C   = (const float*)d_in[5];
    const float* Dp    = (const float*)d_in[6];
    const float* W_out = (const float*)d_in[7];
    const float* ln_g  = (const float*)d_in[8];
    const float* ln_b  = (const float*)d_in[9];

    // workspace layout (bytes). total: 133,693,440 (~128 MB)
    char* p = (char*)d_ws;
    short* xw    = (short*)(p);                 // x bf16 [8192,1024] — LIVE until GEMM4
    short* w1    = (short*)(p +  16777216);     // W_in bf16 — dead after GEMM1
    short* wB    = (short*)(p +  25165824);     // W_B bf16  — dead after GEMM2
    short* wC    = (short*)(p +  25427968);     // W_C bf16  — read by GEMM3
    short* wO    = (short*)(p +  25690112);     // W_out bf16 — read by GEMM4
    short* xproj = (short*)(p +  29884416);     // x_proj bf16 [8192,4096]
    short* u     = (short*)(p +  96993280);     // u bf16 [8192,2048]
    short* hs    = (short*)(p + 132644864);     // hs bf16 [8192,64]
    short* yg    = u;                           // alias: in-place GEMM3 epilogue
    short* yx    = xproj;                       // GEMM4 out bf16(y+x), over dead xproj
    // scan/split-K scratch in DEAD regions (xw survives for GEMM4 EPI=3):
    float* BuP    = (float*)(p + 16777216);     // 4x [8192,64] f32 = 8,388,608 (w1)
    float* locfin = (float*)(p + 25165824);     // 65,536 (wB region, dead post-GEMM2)
    float* carry  = (float*)(p + 25231360);     // 65,536

    const int M = MROWS;  // 8192

    cvt5_kernel<<<(int)((C4_TOT + 255) / 256), 256, 0, stream>>>(
        x, W_in, W_B, W_C, W_out, xw);

    // GEMM1: x_proj = x @ W_in^T  [8192,4096] bf16 — 8-phase + region swizzle
    gemm_8ph<0, 2><<<dim3(2 * INNER / 256, M / 256), 512, 0, stream>>>(
        xw, w1, xproj, M, 2 * INNER, DIMD);

    // conv + silu -> u
    conv_silu_kernel<<<M, 256, 0, stream>>>(xproj, cw, cb, u);

    // GEMM2: BuP[z] = u @ W_B^T partials  [4][8192, 64] f32 (split-K x4)
    gemm_ring<64, 64, 64, 2, 2, 1, 4, 0><<<dim3(1, M / 64, 4), 256, 0, stream>>>(
        u, wB, BuP, M, STATE, INNER, nullptr);

    // chunked parallel scan -> hs (bf16); sums the 4 partials on load
    float decayL;
    {
        double dd = 1.0;
        for (int i = 0; i < CHUNK_L; i++) dd *= 0.95;
        decayL = (float)dd;
    }
    scan_local_kernel<<<BATCH * NCHUNK, STATE, 0, stream>>>(BuP, locfin);
    carry_kernel<<<1, 256, 0, stream>>>(locfin, carry, decayL);
    scan_apply_kernel<<<BATCH * NCHUNK, STATE, 0, stream>>>(BuP, carry, hs);

    // GEMM3 fused: yg = (hs @ W_C^T + D*u) * silu(gate)  [8192, 2048] bf16
    gemm3_fused<<<dim3(INNER / 128, M / 128), 256, 0, stream>>>(
        hs, wC, yg, xproj + INNER, Dp);

    // GEMM4: yx = bf16(yg @ W_out^T + x)  [8192,1024] — round-8 proven config
    gemm_ring<128, 128, 64, 2, 2, 3, 1, 1><<<dim3(DIMD / 128, M / 128), 256, 0, stream>>>(
        yg, wO, yx, M, DIMD, INNER, xw);

    // LayerNorm(yx) -> d_out
    ln_kernel<<<M, 256, 0, stream>>>(yx, ln_g, ln_b, (float*)d_out);
}

// Round 19
// 238.774 us; speedup vs baseline: 1.4217x; 1.0136x over previous
//
#include <hip/hip_runtime.h>
#include <hip/hip_bf16.h>

#define T_SEQ 2048
#define DIMD  1024
#define INNER 2048
#define STATE 64
#define BATCH 4
#define NCHUNK 64
#define CHUNK_L (T_SEQ / NCHUNK)   // 32
#define MROWS (BATCH * T_SEQ)      // 8192
#define PSTRIDE ((long)MROWS * STATE)

typedef __hip_bfloat16 bf16;
typedef __attribute__((ext_vector_type(8))) short bf16x8v;
typedef __attribute__((ext_vector_type(4))) float f32x4v;
typedef __attribute__((ext_vector_type(16))) float f32x16v;
typedef __attribute__((ext_vector_type(4))) short short4v;

__device__ __forceinline__ float b2f(short s) {
    unsigned u = ((unsigned)(unsigned short)s) << 16;
    float f;
    __builtin_memcpy(&f, &u, 4);
    return f;
}
__device__ __forceinline__ short f2b(float f) {
    bf16 h = __float2bfloat16(f);  // RNE
    short s;
    __builtin_memcpy(&s, &h, 2);
    return s;
}

// async global->LDS, 16B per lane. LDS dest must be lane-linear.
__device__ __forceinline__ void gld_lds16(void* lds, const void* gsrc) {
    __builtin_amdgcn_global_load_lds(
        (const __attribute__((address_space(1))) unsigned*)gsrc,
        (__attribute__((address_space(3))) unsigned*)lds, 16, 0, 0);
}

template<int N> __device__ __forceinline__ void waitcnt_vm() {
    if constexpr (N == 8)       asm volatile("s_waitcnt vmcnt(8)" ::: "memory");
    else if constexpr (N == 4)  asm volatile("s_waitcnt vmcnt(4)" ::: "memory");
    else if constexpr (N == 2)  asm volatile("s_waitcnt vmcnt(2)" ::: "memory");
    else                        asm volatile("s_waitcnt vmcnt(0)" ::: "memory");
}
__device__ __forceinline__ void block_barrier() {
    asm volatile("" ::: "memory");
    __builtin_amdgcn_s_barrier();
    asm volatile("" ::: "memory");
}

// Block swizzle. Mode 1: XCD contiguous-chunk (nwg%8==0). Mode 2: region
// (4x4 blocks per region within an XCD strip; L2-resident panel sharing).
template<int XSWZ>
__device__ __forceinline__ void swz_block(int& bx, int& by) {
    if constexpr (XSWZ == 1) {
        const int gx = gridDim.x;
        const int nwg = gx * gridDim.y;
        int id = by * gx + bx;
        const int cpx = nwg >> 3;
        id = (id & 7) * cpx + (id >> 3);
        bx = id % gx; by = id / gx;
    } else if constexpr (XSWZ == 2) {
        const int gx = gridDim.x;
        const int gy = gridDim.y;
        const int id = by * gx + bx;
        const int xcd = id & 7;
        const int c   = id >> 3;
        const int rowsX = gy >> 3;
        const int rw  = gx >> 2;
        const int r   = c >> 4;
        const int pos = c & 15;
        const int rbx = (r % rw) << 2;
        const int rby = (r / rw) << 2;
        bx = rbx + (pos & 3);
        by = xcd * rowsX + rby + (pos >> 2);
    }
}

// ---------------------------------------------------------------------------
// 256^2 GEMM, round 19: v_mfma_f32_32x32x16_bf16 with 64x128 wave tiles.
// Halves LDS-read instructions per FLOP vs the 16x16 shape (24 vs 48
// b128/wave/K-tile) -- the cycle model's binding term.
// Wave grid: 8 waves = 4 row-groups (wr, 64 rows) x 2 col-groups (wc, 128).
// Per K-tile t (BK=64): ONE vmcnt(0)+barrier at top (all 4 halves of t
// resident; staging during t targets buf[(t+1)&1] -- disjoint; the top
// barrier also fences tile t-1's readers before buf[(t+1)&1] overwrite).
// 4 phases h (K16-slices), no inner barriers (waves drift -> cross-wave
// LDS/MFMA overlap): rd 6 frags; stage half h of t+1; lgkm(0)+schedbar
// (rule 18); setprio(1); 8x mfma_32x32x16; setprio(0).
// Frag layouts (canonical; C/D guide-verified m74/m101):
//   A/B: lane holds [row = l&31][k = (l>>5)*8 + j]
//   C/D: col = l&31, row = (reg&3) + 8*(reg>>2) + 4*(l>>5)
// XOR swizzle: physlot = slot ^ (row&7), SAME staging involution as before
// (rule 21); 4 lanes/bank-group = structural b128 minimum, no extra cost.
// ---------------------------------------------------------------------------
template<int EPI, int XSWZ>
__global__ __launch_bounds__(512, 2)
void gemm_8ph(const short* __restrict__ A, const short* __restrict__ B,
              void* __restrict__ Cout, int M, int N, int K)
{
    __shared__ __align__(16) short As[2][2][128 * 64];
    __shared__ __align__(16) short Bs[2][2][128 * 64];

    int bx = blockIdx.x, by = blockIdx.y;
    swz_block<XSWZ>(bx, by);

    const int tid  = threadIdx.x;
    const int lane = tid & 63;
    const int wave = tid >> 6;
    const int wr = wave >> 1;            // 0..3: 64-row group
    const int wc = wave & 1;             // 0..1: 128-col group
    const long bm = (long)by * 256;
    const long bn = (long)bx * 256;

    const int ssrc = (((tid & 7) ^ ((tid >> 3) & 7)) * 8);
    const int lrow = lane & 31;          // row within 32-tile
    const int kgrp = lane >> 5;          // k subgroup (0/1)

    f32x16v acc[2][4];                   // [m 32-row tile][n 32-col tile]
#pragma unroll
    for (int m = 0; m < 2; m++)
#pragma unroll
        for (int n = 0; n < 4; n++)
#pragma unroll
            for (int r = 0; r < 16; r++)
                acc[m][n][r] = 0.f;

    const int nt = K / 64;

    auto stage_half = [&](int tt, int h) {
        const int buf = tt & 1;
        const int half = h >> 1;
        const int k0 = tt * 64;
#pragma unroll
        for (int i = 0; i < 2; i++) {
            const int j = i * 512 + tid;
            if (h & 1)
                gld_lds16(&Bs[buf][half][j * 8],
                          &B[(bn + half * 128 + (j >> 3)) * (long)K + k0 + ssrc]);
            else
                gld_lds16(&As[buf][half][j * 8],
                          &A[(bm + half * 128 + (j >> 3)) * (long)K + k0 + ssrc]);
        }
    };

    // prologue: tile 0's 4 halves in flight
    stage_half(0, 0); stage_half(0, 1); stage_half(0, 2); stage_half(0, 3);

    const int ah  = wr >> 1;             // A half for this wave
    const int ar0 = (wr & 1) * 64;       // A row base within half

    for (int t = 0; t < nt; ++t) {
        const int buf = t & 1;
        const bool pf = (t + 1 < nt);
        waitcnt_vm<0>();                 // all 4 halves of tile t landed
        block_barrier();                 // publish + fence old readers
#pragma unroll
        for (int h = 0; h < 4; ++h) {
            const int slog = h * 2 + kgrp;       // logical 16B slot of k-slice
            bf16x8v af[2], bfv[4];
#pragma unroll
            for (int m = 0; m < 2; m++) {
                const int rin = ar0 + m * 32 + lrow;
                af[m] = *(const bf16x8v*)&As[buf][ah][rin * 64 + ((slog ^ (rin & 7)) * 8)];
            }
#pragma unroll
            for (int n = 0; n < 4; n++) {
                const int rin = n * 32 + lrow;
                bfv[n] = *(const bf16x8v*)&Bs[buf][wc][rin * 64 + ((slog ^ (rin & 7)) * 8)];
            }
            if (pf) stage_half(t + 1, h);

            asm volatile("s_waitcnt lgkmcnt(0)" ::: "memory");
            __builtin_amdgcn_sched_barrier(0);   // rule 18
            __builtin_amdgcn_s_setprio(1);
#pragma unroll
            for (int m = 0; m < 2; m++)
#pragma unroll
                for (int n = 0; n < 4; n++)
                    acc[m][n] = __builtin_amdgcn_mfma_f32_32x32x16_bf16(
                        af[m], bfv[n], acc[m][n], 0, 0, 0);
            __builtin_amdgcn_s_setprio(0);
        }
    }

    // C write: col = lane&31, row = (r&3) + 8*(r>>2) + 4*kgrp (m74/m101)
#pragma unroll
    for (int m = 0; m < 2; m++) {
#pragma unroll
        for (int n = 0; n < 4; n++) {
            const long col = bn + wc * 128 + n * 32 + lrow;
#pragma unroll
            for (int r = 0; r < 16; r++) {
                const long row = bm + wr * 64 + m * 32 + (r & 3) + 8 * (r >> 2) + 4 * kgrp;
                ((short*)Cout)[row * (long)N + col] = f2b(acc[m][n][r]);
            }
        }
    }
}

// ---------------------------------------------------------------------------
// NT GEMM, ring-2 double-buffer with COUNTED vmcnt (round-8 verified config)
// ---------------------------------------------------------------------------
template<int BM, int BN, int BK, int WR, int WC, int EPI, int SPLITK, int XSWZ>
__global__ __launch_bounds__(WR*WC*64, 2)
void gemm_ring(const short* __restrict__ A, const short* __restrict__ B,
               void* __restrict__ Cout, int M, int N, int K,
               const short* __restrict__ u_ptr)
{
    constexpr int MFR = BM / (WR * 16);
    constexpr int NFR = BN / (WC * 16);
    constexpr int THREADS = WR * WC * 64;
    constexpr int UPR = BK / 8;
    constexpr int AISS = (BM * UPR) / THREADS;
    constexpr int BISS = (BN * UPR) / THREADS;
    constexpr int LPS  = AISS + BISS;
    __shared__ __align__(16) short As[2][BM * BK];
    __shared__ __align__(16) short Bs[2][BN * BK];

    int bx = blockIdx.x, by = blockIdx.y;
    swz_block<XSWZ>(bx, by);

    const int tid  = threadIdx.x;
    const int lane = tid & 63;
    const int wave = tid >> 6;
    const int wm = (wave / WC) * (MFR * 16);
    const int wn = (wave % WC) * (NFR * 16);
    const long bm = (long)by * BM;
    const long bn = (long)bx * BN;

    f32x4v acc[MFR][NFR];
#pragma unroll
    for (int m = 0; m < MFR; m++)
#pragma unroll
        for (int n = 0; n < NFR; n++)
            acc[m][n] = (f32x4v){0.f, 0.f, 0.f, 0.f};

    const int rsel = lane & 15;
    const int ssrc = (((tid & 7) ^ ((tid >> 3) & 7)) * 8);
    const int swz  = lane & 7;

    int kbeg = 0, kend = K;
    if constexpr (SPLITK > 1) {
        const int kch = K / SPLITK;
        kbeg = blockIdx.z * kch;
        kend = kbeg + kch;
    }
    const int nt = (kend - kbeg) / BK;

    auto stage = [&](int buf, int k0) {
#pragma unroll
        for (int i = 0; i < AISS; i++) {
            const int j = i * THREADS + tid;
            gld_lds16(&As[buf][j * 8],
                      &A[(bm + (j >> 3)) * (long)K + k0 + ssrc]);
        }
#pragma unroll
        for (int i = 0; i < BISS; i++) {
            const int j = i * THREADS + tid;
            gld_lds16(&Bs[buf][j * 8],
                      &B[(bn + (j >> 3)) * (long)K + k0 + ssrc]);
        }
    };
    auto compute = [&](int buf) {
#pragma unroll
        for (int kk = 0; kk < BK; kk += 32) {
            const int slog = (kk >> 3) + (lane >> 4);
            const int soff = ((slog ^ swz) * 8);
            bf16x8v af[MFR], bfv[NFR];
#pragma unroll
            for (int m = 0; m < MFR; m++)
                af[m] = *(const bf16x8v*)&As[buf][(wm + m * 16 + rsel) * BK + soff];
#pragma unroll
            for (int n = 0; n < NFR; n++)
                bfv[n] = *(const bf16x8v*)&Bs[buf][(wn + n * 16 + rsel) * BK + soff];
#pragma unroll
            for (int m = 0; m < MFR; m++)
#pragma unroll
                for (int n = 0; n < NFR; n++)
                    acc[m][n] = __builtin_amdgcn_mfma_f32_16x16x32_bf16(
                        af[m], bfv[n], acc[m][n], 0, 0, 0);
        }
    };

    stage(0, kbeg);
    for (int t = 0; t < nt; ++t) {
        const bool pf = (t + 1 < nt);
        if (pf) stage((t + 1) & 1, kbeg + (t + 1) * BK);
        if (pf) waitcnt_vm<LPS>();
        else    waitcnt_vm<0>();
        block_barrier();
        compute(t & 1);
        block_barrier();
    }

    float* fout = (float*)Cout;
    if constexpr (SPLITK > 1)
        fout += (long)blockIdx.z * (long)M * N;

#pragma unroll
    for (int m = 0; m < MFR; m++) {
#pragma unroll
        for (int n = 0; n < NFR; n++) {
            const long col  = bn + wn + n * 16 + (lane & 15);
            const long row0 = bm + wm + m * 16 + (lane >> 4) * 4;
#pragma unroll
            for (int j = 0; j < 4; j++) {
                const long row = row0 + j;
                const float v = acc[m][n][j];
                const long idx = row * (long)N + col;
                if constexpr (EPI == 0) {
                    ((short*)Cout)[idx] = f2b(v);
                } else if constexpr (EPI == 1) {
                    fout[idx] = v;
                } else {   // EPI == 3: + residual x, store bf16
                    ((short*)Cout)[idx] = f2b(v + b2f(u_ptr[idx]));
                }
            }
        }
    }
}

// ---------------------------------------------------------------------------
// depthwise causal conv1d(k=4, left-pad 3) + bias + SiLU
// ---------------------------------------------------------------------------
__global__ __launch_bounds__(256)
void conv_silu_kernel(const short* __restrict__ xproj, const float* __restrict__ cw,
                      const float* __restrict__ cb, short* __restrict__ u)
{
    const int bt = blockIdx.x;
    const int t  = bt & (T_SEQ - 1);
    const int c0 = threadIdx.x * 8;

    float wreg[4][8];
#pragma unroll
    for (int i = 0; i < 8; i++) {
        float4 wv = *(const float4*)&cw[(c0 + i) * 4];
        wreg[0][i] = wv.x; wreg[1][i] = wv.y; wreg[2][i] = wv.z; wreg[3][i] = wv.w;
    }
    float acc[8];
#pragma unroll
    for (int i = 0; i < 8; i++) acc[i] = cb[c0 + i];

#pragma unroll
    for (int k = 0; k < 4; k++) {
        if (t - 3 + k < 0) continue;
        bf16x8v v = *(const bf16x8v*)&xproj[(long)(bt - 3 + k) * (2 * INNER) + c0];
#pragma unroll
        for (int i = 0; i < 8; i++) acc[i] += b2f(v[i]) * wreg[k][i];
    }
    short o[8];
#pragma unroll
    for (int i = 0; i < 8; i++) {
        float s = acc[i] / (1.f + __expf(-acc[i]));
        o[i] = f2b(s);
    }
    *(bf16x8v*)&u[(long)bt * INNER + c0] = *(const bf16x8v*)o;
}

// ---------------------------------------------------------------------------
// GEMM3 fused (K=64, nt=1): y = hs @ W_C^T; yg = (y + D*u) * silu(gate).
// ---------------------------------------------------------------------------
#define EBS 132
__global__ __launch_bounds__(256, 2)
void gemm3_fused(const short* __restrict__ hs, const short* __restrict__ Wc,
                 short* __restrict__ yg, const short* __restrict__ gate_ptr,
                 const float* __restrict__ Dp)
{
    __shared__ __align__(16) short As[128 * 64];
    __shared__ __align__(16) short Bs[128 * 64];
    __shared__ __align__(16) float eb[64 * EBS];

    const int tid  = threadIdx.x;
    const int lane = tid & 63;
    const int wave = tid >> 6;
    const int wm = (wave >> 1) * 64;
    const int wn = (wave & 1) * 64;
    const long bm = (long)blockIdx.y * 128;
    const long bn = (long)blockIdx.x * 128;

    const int rsel = lane & 15;
    const int ssrc = (((tid & 7) ^ ((tid >> 3) & 7)) * 8);
    const int swz  = lane & 7;

#pragma unroll
    for (int i = 0; i < 4; i++) {
        const int j = i * 256 + tid;
        gld_lds16(&As[j * 8], &hs[(bm + (j >> 3)) * (long)STATE + ssrc]);
    }
#pragma unroll
    for (int i = 0; i < 4; i++) {
        const int j = i * 256 + tid;
        gld_lds16(&Bs[j * 8], &Wc[(bn + (j >> 3)) * (long)STATE + ssrc]);
    }
    waitcnt_vm<0>();
    block_barrier();

    f32x4v acc[4][4];
#pragma unroll
    for (int m = 0; m < 4; m++)
#pragma unroll
        for (int n = 0; n < 4; n++)
            acc[m][n] = (f32x4v){0.f, 0.f, 0.f, 0.f};

#pragma unroll
    for (int kk = 0; kk < 64; kk += 32) {
        const int slog = (kk >> 3) + (lane >> 4);
        const int soff = ((slog ^ swz) * 8);
        bf16x8v af[4], bfv[4];
#pragma unroll
        for (int m = 0; m < 4; m++)
            af[m] = *(const bf16x8v*)&As[(wm + m * 16 + rsel) * 64 + soff];
#pragma unroll
        for (int n = 0; n < 4; n++)
            bfv[n] = *(const bf16x8v*)&Bs[(wn + n * 16 + rsel) * 64 + soff];
#pragma unroll
        for (int m = 0; m < 4; m++)
#pragma unroll
            for (int n = 0; n < 4; n++)
                acc[m][n] = __builtin_amdgcn_mfma_f32_16x16x32_bf16(
                    af[m], bfv[n], acc[m][n], 0, 0, 0);
    }

#pragma unroll
    for (int p = 0; p < 2; p++) {
        block_barrier();
        if ((wm >> 6) == p) {
#pragma unroll
            for (int m = 0; m < 4; m++) {
#pragma unroll
                for (int n = 0; n < 4; n++) {
                    const int cl = wn + n * 16 + (lane & 15);
#pragma unroll
                    for (int j = 0; j < 4; j++) {
                        const int rl = m * 16 + (lane >> 4) * 4 + j;
                        eb[rl * EBS + cl] = acc[m][n][j];
                    }
                }
            }
        }
        block_barrier();
#pragma unroll
        for (int k = 0; k < 4; k++) {
            const int unit = k * 256 + tid;
            const int rl = unit >> 4, cg = (unit & 15) * 8;
            const long grow = bm + p * 64 + rl;
            const long gcol = bn + cg;
            f32x4v y0 = *(const f32x4v*)&eb[rl * EBS + cg];
            f32x4v y1 = *(const f32x4v*)&eb[rl * EBS + cg + 4];
            bf16x8v uv = *(const bf16x8v*)&yg[grow * (long)INNER + gcol];
            bf16x8v gv = *(const bf16x8v*)&gate_ptr[grow * (long)(2 * INNER) + gcol];
            short o[8];
#pragma unroll
            for (int i = 0; i < 8; i++) {
                const float yy = (i < 4 ? y0[i] : y1[i - 4]);
                const float uu = b2f(uv[i]);
                const float gg = b2f(gv[i]);
                const float yv = yy + Dp[gcol + i] * uu;
                const float sg = gg / (1.f + __expf(-gg));
                o[i] = f2b(yv * sg);
            }
            *(bf16x8v*)&yg[grow * (long)INNER + gcol] = *(const bf16x8v*)o;
        }
    }
}

// ---------------------------------------------------------------------------
// Chunked parallel scan; Bu given as 4 split-K partials (stride PSTRIDE)
// ---------------------------------------------------------------------------
__global__ __launch_bounds__(64)
void scan_local_kernel(const float* __restrict__ Bu, float* __restrict__ locfin)
{
    const int b  = blockIdx.x / NCHUNK;
    const int ch = blockIdx.x % NCHUNK;
    const long base = ((long)b * T_SEQ + (long)ch * CHUNK_L) * STATE + threadIdx.x;
    float h = 0.f;
#pragma unroll
    for (int t = 0; t < CHUNK_L; t++) {
        const long o = base + (long)t * STATE;
        float bu = (Bu[o] + Bu[o + PSTRIDE]) + (Bu[o + 2 * PSTRIDE] + Bu[o + 3 * PSTRIDE]);
        h = 0.95f * h + 0.05f * bu;
    }
    locfin[(long)blockIdx.x * STATE + threadIdx.x] = h;
}

__global__ __launch_bounds__(256)
void carry_kernel(const float* __restrict__ locfin, float* __restrict__ carry,
                  float decayL)
{
    __shared__ float sm[BATCH * NCHUNK * STATE];
    for (int i = threadIdx.x; i < BATCH * NCHUNK * STATE; i += 256)
        sm[i] = locfin[i];
    __syncthreads();
    const int b = threadIdx.x >> 6, s = threadIdx.x & 63;
    float c = 0.f;
    for (int ch = 0; ch < NCHUNK; ch++) {
        const int idx = (b * NCHUNK + ch) * STATE + s;
        carry[idx] = c;
        c = decayL * c + sm[idx];
    }
}

__global__ __launch_bounds__(64)
void scan_apply_kernel(const float* __restrict__ Bu, const float* __restrict__ carry,
                       short* __restrict__ hs)
{
    const int b  = blockIdx.x / NCHUNK;
    const int ch = blockIdx.x % NCHUNK;
    const long base = ((long)b * T_SEQ + (long)ch * CHUNK_L) * STATE + threadIdx.x;
    float h = carry[(long)blockIdx.x * STATE + threadIdx.x];
#pragma unroll
    for (int t = 0; t < CHUNK_L; t++) {
        const long o = base + (long)t * STATE;
        float bu = (Bu[o] + Bu[o + PSTRIDE]) + (Bu[o + 2 * PSTRIDE] + Bu[o + 3 * PSTRIDE]);
        h = 0.95f * h + 0.05f * bu;
        hs[o] = f2b(h);
    }
}

// ---------------------------------------------------------------------------
// LayerNorm over pre-summed bf16 (y + x) -> out (f32)
// ---------------------------------------------------------------------------
__global__ __launch_bounds__(256)
void ln_kernel(const short* __restrict__ yx, const float* __restrict__ g,
               const float* __restrict__ b, float* __restrict__ out)
{
    const int row = blockIdx.x;
    const int c   = threadIdx.x * 4;
    const long off = (long)row * DIMD + c;
    const short4v yv = *(const short4v*)&yx[off];
    float s0 = b2f(yv[0]), s1 = b2f(yv[1]), s2 = b2f(yv[2]), s3 = b2f(yv[3]);
    float sum = s0 + s1 + s2 + s3;
    float sq  = s0 * s0 + s1 * s1 + s2 * s2 + s3 * s3;
#pragma unroll
    for (int o = 32; o > 0; o >>= 1) {
        sum += __shfl_down(sum, o);
        sq  += __shfl_down(sq, o);
    }
    __shared__ float rs[4], rq[4];
    const int wave = threadIdx.x >> 6, lane = threadIdx.x & 63;
    if (lane == 0) { rs[wave] = sum; rq[wave] = sq; }
    __syncthreads();
    float tsum = rs[0] + rs[1] + rs[2] + rs[3];
    float tsq  = rq[0] + rq[1] + rq[2] + rq[3];
    float mu  = tsum * (1.f / DIMD);
    float inv = rsqrtf(tsq * (1.f / DIMD) - mu * mu + 1e-5f);
    float4 gv = *(const float4*)&g[c];
    float4 bv = *(const float4*)&b[c];
    float4 ov;
    ov.x = (s0 - mu) * inv * gv.x + bv.x;
    ov.y = (s1 - mu) * inv * gv.y + bv.y;
    ov.z = (s2 - mu) * inv * gv.z + bv.z;
    ov.w = (s3 - mu) * inv * gv.w + bv.w;
    *(float4*)&out[off] = ov;
}

// ---------------------------------------------------------------------------
// fused f32->bf16 convert of all 5 tensors into the contiguous ws region
// ---------------------------------------------------------------------------
#define C4_X   2097152L
#define C4_W1  (C4_X + 1048576L)
#define C4_WB  (C4_W1 + 32768L)
#define C4_WC  (C4_WB + 32768L)
#define C4_TOT (C4_WC + 524288L)

__global__ __launch_bounds__(256)
void cvt5_kernel(const float* __restrict__ x, const float* __restrict__ w1,
                 const float* __restrict__ wB, const float* __restrict__ wC,
                 const float* __restrict__ wO, short* __restrict__ dst)
{
    const long i = (long)blockIdx.x * 256 + threadIdx.x;
    if (i >= C4_TOT) return;
    const float* s;
    long off;
    if      (i < C4_X)  { s = x;  off = i; }
    else if (i < C4_W1) { s = w1; off = i - C4_X; }
    else if (i < C4_WB) { s = wB; off = i - C4_W1; }
    else if (i < C4_WC) { s = wC; off = i - C4_WB; }
    else                { s = wO; off = i - C4_WC; }
    float4 v = *(const float4*)&s[off * 4];
    short4v o = { f2b(v.x), f2b(v.y), f2b(v.z), f2b(v.w) };
    *(short4v*)&dst[i * 4] = o;
}

extern "C" void kernel_launch(void* const* d_in, const int* in_sizes, int n_in,
                              void* d_out, int out_size, void* d_ws, size_t ws_size,
                              hipStream_t stream)
{
    const float* x     = (const float*)d_in[0];
    const float* W_in  = (const float*)d_in[1];
    const float* cw    = (const float*)d_in[2];
    const float* cb    = (const float*)d_in[3];
    const float* W_B   = (const float*)d_in[4];
    const float* W_C   = (const float*)d_in[5];
    const float* Dp    = (const float*)d_in[6];
    const float* W_out = (const float*)d_in[7];
    const float* ln_g  = (const float*)d_in[8];
    const float* ln_b  = (const float*)d_in[9];

    // workspace layout (bytes). total: 133,693,440 (~128 MB)
    char* p = (char*)d_ws;
    short* xw    = (short*)(p);                 // x bf16 [8192,1024] — LIVE until GEMM4
    short* w1    = (short*)(p +  16777216);     // W_in bf16 — dead after GEMM1
    short* wB    = (short*)(p +  25165824);     // W_B bf16  — dead after GEMM2
    short* wC    = (short*)(p +  25427968);     // W_C bf16  — read by GEMM3
    short* wO    = (short*)(p +  25690112);     // W_out bf16 — read by GEMM4
    short* xproj = (short*)(p +  29884416);     // x_proj bf16 [8192,4096]
    short* u     = (short*)(p +  96993280);     // u bf16 [8192,2048]
    short* hs    = (short*)(p + 132644864);     // hs bf16 [8192,64]
    short* yg    = u;                           // alias: in-place GEMM3 epilogue
    short* yx    = xproj;                       // GEMM4 out bf16(y+x), over dead xproj
    // scan/split-K scratch in DEAD regions (xw survives for GEMM4 EPI=3):
    float* BuP    = (float*)(p + 16777216);     // 4x [8192,64] f32 = 8,388,608 (w1)
    float* locfin = (float*)(p + 25165824);     // 65,536 (wB region, dead post-GEMM2)
    float* carry  = (float*)(p + 25231360);     // 65,536

    const int M = MROWS;  // 8192

    cvt5_kernel<<<(int)((C4_TOT + 255) / 256), 256, 0, stream>>>(
        x, W_in, W_B, W_C, W_out, xw);

    // GEMM1: x_proj = x @ W_in^T  [8192,4096] bf16 — 32x32x16 wave-wide 8ph
    gemm_8ph<0, 2><<<dim3(2 * INNER / 256, M / 256), 512, 0, stream>>>(
        xw, w1, xproj, M, 2 * INNER, DIMD);

    // conv + silu -> u
    conv_silu_kernel<<<M, 256, 0, stream>>>(xproj, cw, cb, u);

    // GEMM2: BuP[z] = u @ W_B^T partials  [4][8192, 64] f32 (split-K x4)
    gemm_ring<64, 64, 64, 2, 2, 1, 4, 0><<<dim3(1, M / 64, 4), 256, 0, stream>>>(
        u, wB, BuP, M, STATE, INNER, nullptr);

    // chunked parallel scan -> hs (bf16); sums the 4 partials on load
    float decayL;
    {
        double dd = 1.0;
        for (int i = 0; i < CHUNK_L; i++) dd *= 0.95;
        decayL = (float)dd;
    }
    scan_local_kernel<<<BATCH * NCHUNK, STATE, 0, stream>>>(BuP, locfin);
    carry_kernel<<<1, 256, 0, stream>>>(locfin, carry, decayL);
    scan_apply_kernel<<<BATCH * NCHUNK, STATE, 0, stream>>>(BuP, carry, hs);

    // GEMM3 fused: yg = (hs @ W_C^T + D*u) * silu(gate)  [8192, 2048] bf16
    gemm3_fused<<<dim3(INNER / 128, M / 128), 256, 0, stream>>>(
        hs, wC, yg, xproj + INNER, Dp);

    // GEMM4: yx = bf16(yg @ W_out^T + x)  [8192,1024] — round-8 proven config
    gemm_ring<128, 128, 64, 2, 2, 3, 1, 1><<<dim3(DIMD / 128, M / 128), 256, 0, stream>>>(
        yg, wO, yx, M, DIMD, INNER, xw);

    // LayerNorm(yx) -> d_out
    ln_kernel<<<M, 256, 0, stream>>>(yx, ln_g, ln_b, (float*)d_out);
}